// Round 3
// baseline (790.728 us; speedup 1.0000x reference)
//
#include <hip/hip_runtime.h>
#include <utility>

typedef unsigned int  u32;
typedef unsigned short u16;

// ======================= compile-time real-CG generation =======================
// Mirrors the Python reference exactly: _cg (Clebsch-Gordan), _u (real<-complex
// SH change of basis), _real_cg (einsum + pick R or I by abs-sum), all in double.

struct CEnt { int i, j, k; double c; };
struct PathTab { int n; int s; bool ku[9]; CEnt e[400]; };
struct cxd { double re, im; };
struct URow { int n; int col[2]; cxd v[2]; };
struct MTab { double M[9][9][9]; };

constexpr double FT[14] = {1.,1.,2.,6.,24.,120.,720.,5040.,40320.,362880.,
                           3628800.,39916800.,479001600.,6227020800.};

constexpr double cabs_(double x){ return x < 0 ? -x : x; }

constexpr double csqrt_(double x){
  if (x <= 0.) return 0.;
  double g = 1.;
  while (g*g < x) g *= 2.;
  for (int it = 0; it < 50; ++it) g = 0.5*(g + x/g);
  return g;
}

constexpr double cg_(int j1,int m1,int j2,int m2,int j3,int m3){
  if (m1 + m2 != m3) return 0.;
  int dj = j1 - j2; if (dj < 0) dj = -dj;
  if (j3 < dj || j3 > j1 + j2) return 0.;
  double preA = (double)(2*j3+1)*FT[j3+j1-j2]*FT[j3-j1+j2]*FT[j1+j2-j3]/FT[j1+j2+j3+1];
  double preB = FT[j3+m3]*FT[j3-m3]*FT[j1-m1]*FT[j1+m1]*FT[j2-m2]*FT[j2+m2];
  double pre = csqrt_(preA)*csqrt_(preB);
  int kmin = 0;
  if (j2-j3-m1 > kmin) kmin = j2-j3-m1;
  if (j1-j3+m2 > kmin) kmin = j1-j3+m2;
  int kmax = j1+j2-j3;
  if (j1-m1 < kmax) kmax = j1-m1;
  if (j2+m2 < kmax) kmax = j2+m2;
  double s = 0.;
  for (int k = kmin; k <= kmax; ++k){
    double d = FT[k]*FT[j1+j2-j3-k]*FT[j1-m1-k]*FT[j2+m2-k]*FT[j3-j2+m1+k]*FT[j3-j1-m2+k];
    s += ((k & 1) ? -1.0 : 1.0)/d;
  }
  return pre*s;
}

constexpr URow urow_(int l, int r){
  URow R{};
  const double s2 = 0.7071067811865476; // 2**-0.5
  int m = r - l;
  if (m == 0){ R.n = 1; R.col[0] = l; R.v[0] = {1., 0.}; }
  else if (m > 0){
    R.n = 2;
    R.col[0] = l + m; R.v[0] = { (m & 1) ? -s2 : s2, 0. };
    R.col[1] = l - m; R.v[1] = { s2, 0. };
  } else {
    int mm = -m;
    R.n = 2;
    R.col[0] = l - mm; R.v[0] = { 0., s2 };
    R.col[1] = l + mm; R.v[1] = { 0., (mm & 1) ? s2 : -s2 };
  }
  return R;
}

constexpr cxd cmul_(cxd a, cxd b){ return { a.re*b.re - a.im*b.im, a.re*b.im + a.im*b.re }; }

// Selected (R or I by abs-sum, exactly like the reference) real CG tensor.
constexpr MTab buildM(int l1, int l2, int l3){
  const int n1 = 2*l1+1, n2 = 2*l2+1, n3 = 2*l3+1;
  double cgd[9][9][9] = {};
  for (int a = 0; a < n1; ++a)
    for (int b = 0; b < n2; ++b)
      for (int c = 0; c < n3; ++c)
        cgd[a][b][c] = cg_(l1, a-l1, l2, b-l2, l3, c-l3);

  double MR[9][9][9] = {}; double MI[9][9][9] = {};
  double sR = 0., sI = 0.;
  for (int i = 0; i < n1; ++i){
    URow u1 = urow_(l1, i);
    for (int j = 0; j < n2; ++j){
      URow u2 = urow_(l2, j);
      for (int k = 0; k < n3; ++k){
        URow u3 = urow_(l3, k);
        double mre = 0., mim = 0.;
        for (int a = 0; a < u1.n; ++a)
          for (int b = 0; b < u2.n; ++b)
            for (int c = 0; c < u3.n; ++c){
              double cv = cgd[u1.col[a]][u2.col[b]][u3.col[c]];
              if (cv != 0.){
                cxd t = cmul_(u1.v[a], u2.v[b]);
                cxd u3c = { u3.v[c].re, -u3.v[c].im };
                t = cmul_(t, u3c);
                mre += t.re*cv; mim += t.im*cv;
              }
            }
        MR[i][j][k] = mre; MI[i][j][k] = mim;
        sR += cabs_(mre); sI += cabs_(mim);
      }
    }
  }
  const bool useR = (sR >= sI);
  MTab out{};
  for (int i = 0; i < n1; ++i)
    for (int j = 0; j < n2; ++j)
      for (int k = 0; k < n3; ++k)
        out.M[i][j][k] = useR ? MR[i][j][k] : MI[i][j][k];
  return out;
}

// Diagonal family (l1==l2): merge (i,j)/(j,i), i<=j. Exact regrouping (y1==y2).
constexpr PathTab buildDiag(int l, int l3){
  MTab A = buildM(l, l, l3);
  PathTab P{}; P.n = 0; P.s = 1;
  const int n = 2*l+1, n3 = 2*l3+1;
  for (int i = 0; i < n; ++i)
    for (int j = i; j < n; ++j)
      for (int k = 0; k < n3; ++k){
        double v = A.M[i][j][k];
        if (j > i) v += A.M[j][i][k];
        if (cabs_(v) > 1e-12){
          if (P.n >= 400) { P.n = -1; return P; }
          P.e[P.n].i = i; P.e[P.n].j = j; P.e[P.n].k = k; P.e[P.n].c = v;
          P.ku[k] = true; P.n++;
        }
      }
  return P;
}

// Off-diagonal pair (l1<l2): verify C21[j,i,k] == s*C12[i,j,k] (s=+-1) and emit
// one merged table; runtime weight becomes w_p + s*w_p'. s==0 -> fallback.
constexpr PathTab buildPair(int l1, int l2, int l3){
  MTab A = buildM(l1, l2, l3);
  MTab B = buildM(l2, l1, l3);
  const int n1 = 2*l1+1, n2 = 2*l2+1, n3 = 2*l3+1;
  bool okp = true, okm = true;
  for (int i = 0; i < n1; ++i)
    for (int j = 0; j < n2; ++j)
      for (int k = 0; k < n3; ++k){
        double a = A.M[i][j][k], b = B.M[j][i][k];
        if (cabs_(b - a) > 1e-9) okp = false;
        if (cabs_(b + a) > 1e-9) okm = false;
      }
  PathTab P{}; P.n = 0; P.s = okp ? 1 : (okm ? -1 : 0);
  if (P.s == 0) return P;
  for (int i = 0; i < n1; ++i)
    for (int j = 0; j < n2; ++j)
      for (int k = 0; k < n3; ++k){
        double v = A.M[i][j][k];
        if (cabs_(v) > 1e-12){
          if (P.n >= 400) { P.n = -1; return P; }
          P.e[P.n].i = i; P.e[P.n].j = j; P.e[P.n].k = k; P.e[P.n].c = v;
          P.ku[k] = true; P.n++;
        }
      }
  return P;
}

// Raw single path (fallback only).
constexpr PathTab buildSingleTab(int l1, int l2, int l3){
  MTab A = buildM(l1, l2, l3);
  const int n1 = 2*l1+1, n2 = 2*l2+1, n3 = 2*l3+1;
  PathTab P{}; P.n = 0; P.s = 1;
  for (int i = 0; i < n1; ++i)
    for (int j = 0; j < n2; ++j)
      for (int k = 0; k < n3; ++k){
        double v = A.M[i][j][k];
        if (cabs_(v) > 1e-12){
          if (P.n >= 400) { P.n = -1; return P; }
          P.e[P.n].i = i; P.e[P.n].j = j; P.e[P.n].k = k; P.e[P.n].c = v;
          P.ku[k] = true; P.n++;
        }
      }
  return P;
}

template<int L,int L3>          struct TD_ { static constexpr PathTab t = buildDiag(L, L3); };
template<int L1,int L2,int L3>  struct TP_ { static constexpr PathTab t = buildPair(L1, L2, L3); };
template<int L1,int L2,int L3>  struct TS_ { static constexpr PathTab t = buildSingleTab(L1, L2, L3); };

// weight index in the reference's path enumeration
constexpr int pidx(int lin, int lout, int a, int b, int c){
  int p = 0;
  for (int l1 = 0; l1 <= lin; ++l1)
    for (int l2 = 0; l2 <= lin; ++l2){
      int lo = l1 > l2 ? l1 - l2 : l2 - l1;
      int hi = (l1 + l2 < lout) ? l1 + l2 : lout;
      for (int l3 = lo; l3 <= hi; ++l3){
        if (l1 == a && l2 == b && l3 == c) return p;
        ++p;
      }
    }
  return -1;
}

// ======================= unrolled per-path contraction =======================
// pacc[k] += c * (yi*yj)  (1 fma/entry, products CSE'd by GVN),
// then o[k] += we * pacc[k] once per used k.

template<class TT,int L1,int L2,int...S>
__device__ __forceinline__ void acc_entries_(const float* __restrict__ y,
                                             float* __restrict__ pacc,
                                             std::integer_sequence<int, S...>){
  (( pacc[TT::t.e[S].k] +=
       (float)TT::t.e[S].c
       * (y[L1*L1 + TT::t.e[S].i] * y[L2*L2 + TT::t.e[S].j]) ), ...);
}

template<class TT,int L3,int K>
__device__ __forceinline__ void wf1_(float* __restrict__ o,
                                     const float* __restrict__ pacc, float we){
  if constexpr (TT::t.ku[K]) o[L3*L3 + K] += we * pacc[K];
}

template<class TT,int L3,int...K>
__device__ __forceinline__ void wfold_(float* __restrict__ o,
                                       const float* __restrict__ pacc, float we,
                                       std::integer_sequence<int, K...>){
  ( wf1_<TT,L3,K>(o, pacc, we), ... );
}

template<class TT,int L1,int L2,int L3>
__device__ __forceinline__ void apply_tab_(const float* __restrict__ y,
                                           float* __restrict__ o, float we){
  float pacc[2*L3+1];
#pragma unroll
  for (int k = 0; k < 2*L3+1; ++k) pacc[k] = 0.f;
  acc_entries_<TT,L1,L2>(y, pacc, std::make_integer_sequence<int, TT::t.n>{});
  wfold_<TT,L3>(o, pacc, we, std::make_integer_sequence<int, 2*L3+1>{});
}

// ======================= path group lists =======================
// Stage 1 (lin=3, lout=4)
#define DIAG1(X) X(0,0) X(1,0) X(1,1) X(1,2) X(2,0) X(2,1) X(2,2) X(2,3) X(2,4) \
                 X(3,0) X(3,1) X(3,2) X(3,3) X(3,4)
#define PAIR1(X) X(0,1,1) X(0,2,2) X(0,3,3) X(1,2,1) X(1,2,2) X(1,2,3) \
                 X(1,3,2) X(1,3,3) X(1,3,4) X(2,3,1) X(2,3,2) X(2,3,3) X(2,3,4)
// Stage 2 (lin=4, lout=4)
#define DIAG2(X) X(0,0) X(1,0) X(1,1) X(1,2) X(2,0) X(2,1) X(2,2) X(2,3) X(2,4) \
                 X(3,0) X(3,1) X(3,2) X(3,3) X(3,4) X(4,0) X(4,1) X(4,2) X(4,3) X(4,4)
#define PAIR2(X) X(0,1,1) X(0,2,2) X(0,3,3) X(0,4,4) X(1,2,1) X(1,2,2) X(1,2,3) \
                 X(1,3,2) X(1,3,3) X(1,3,4) X(1,4,3) X(1,4,4) X(2,3,1) X(2,3,2) \
                 X(2,3,3) X(2,3,4) X(2,4,2) X(2,4,3) X(2,4,4) X(3,4,1) X(3,4,2) \
                 X(3,4,3) X(3,4,4)

// ======================= main kernel =======================

__global__ __launch_bounds__(256) void acmd_kernel(
    const float* __restrict__ disp,
    const float* __restrict__ w1g,
    const float* __restrict__ w2g,
    float* __restrict__ outf, int E)
{
  __shared__ float w1s[40*16];
  __shared__ float w2s[65*16];
  __shared__ float tilef[6400];   // 16 edges * 400 f32

  for (int i = threadIdx.x; i < 40*16; i += 256) w1s[i] = w1g[i];
  for (int i = threadIdx.x; i < 65*16; i += 256) w2s[i] = w2g[i];
  __syncthreads();

  const int le = threadIdx.x >> 4;     // local edge 0..15
  const int f  = threadIdx.x & 15;     // radial channel 0..15
  const int e  = blockIdx.x*16 + le;

  float out[25];
#pragma unroll
  for (int k = 0; k < 25; ++k) out[k] = 0.f;

  if (e < E){
    const float dx = disp[3*e+0], dy = disp[3*e+1], dz = disp[3*e+2];
    const float r  = sqrtf(dx*dx + dy*dy + dz*dz);
    const float x  = r * (1.0f/5.0f);                 // r / CUTOFF
    const float inv = 1.0f / fmaxf(r, 1e-9f);
    const float ux = dx*inv, uy = dy*inv, uz = dz*inv;

    const float cut = (x < 1.0f) ? expf(1.0f - 1.0f/(1.0f - x*x)) : 0.0f;

    // radial: sinc(x*(f+1))
    const float tt = x * (float)(f + 1);
    const float pt = 3.14159265358979f * tt;
    const float rb = (pt > 1e-5f) ? (sinf(pt)/pt) : (1.0f - pt*pt*(1.0f/6.0f));
    const float cr = cut * rb;   // fold cut*rb into shp (exact regroup of rb2*cut2)

    const float sx2 = ux*ux, sy2 = uy*uy, sz2 = uz*uz;
    float shp[16];
    shp[0]  = 0.28209479177387814f;
    shp[1]  = 0.4886025119029199f*uy;
    shp[2]  = 0.4886025119029199f*uz;
    shp[3]  = 0.4886025119029199f*ux;
    shp[4]  = 1.0925484305920792f*ux*uy;
    shp[5]  = 1.0925484305920792f*uy*uz;
    shp[6]  = 0.31539156525252005f*(3.0f*sz2 - 1.0f);
    shp[7]  = 1.0925484305920792f*ux*uz;
    shp[8]  = 0.5462742152960396f*(sx2 - sy2);
    shp[9]  = 0.5900435899266435f*uy*(3.0f*sx2 - sy2);
    shp[10] = 2.890611442640554f*ux*uy*uz;
    shp[11] = 0.4570457994644658f*uy*(5.0f*sz2 - 1.0f);
    shp[12] = 0.3731763325901154f*uz*(5.0f*sz2 - 3.0f);
    shp[13] = 0.4570457994644658f*ux*(5.0f*sz2 - 1.0f);
    shp[14] = 1.445305721320277f*uz*(sx2 - sy2);
    shp[15] = 0.5900435899266435f*ux*(sx2 - 3.0f*sy2);
#pragma unroll
    for (int i = 0; i < 16; ++i) shp[i] *= cr;

    // ---------- stage 1 ----------
    float z1[25];
#pragma unroll
    for (int k = 0; k < 25; ++k) z1[k] = 0.f;

#define D1(l,l3) apply_tab_<TD_<l,l3>, l, l, l3>(shp, z1, w1s[pidx(3,4,l,l,l3)*16 + f]);
    DIAG1(D1)
#undef D1
#define P1(a,b,c) { \
      constexpr int pA = pidx(3,4,a,b,c), pB = pidx(3,4,b,a,c); \
      if constexpr (TP_<a,b,c>::t.s != 0) { \
        const float we = fmaf((float)TP_<a,b,c>::t.s, w1s[pB*16 + f], w1s[pA*16 + f]); \
        apply_tab_<TP_<a,b,c>, a, b, c>(shp, z1, we); \
      } else { \
        apply_tab_<TS_<a,b,c>, a, b, c>(shp, z1, w1s[pA*16 + f]); \
        apply_tab_<TS_<b,a,c>, b, a, c>(shp, z1, w1s[pB*16 + f]); \
      } }
    PAIR1(P1)
#undef P1

    // ---------- stage 2 ----------
#define D2(l,l3) apply_tab_<TD_<l,l3>, l, l, l3>(z1, out, w2s[pidx(4,4,l,l,l3)*16 + f]);
    DIAG2(D2)
#undef D2
#define P2(a,b,c) { \
      constexpr int pA = pidx(4,4,a,b,c), pB = pidx(4,4,b,a,c); \
      if constexpr (TP_<a,b,c>::t.s != 0) { \
        const float we = fmaf((float)TP_<a,b,c>::t.s, w2s[pB*16 + f], w2s[pA*16 + f]); \
        apply_tab_<TP_<a,b,c>, a, b, c>(z1, out, we); \
      } else { \
        apply_tab_<TS_<a,b,c>, a, b, c>(z1, out, w2s[pA*16 + f]); \
        apply_tab_<TS_<b,a,c>, b, a, c>(z1, out, w2s[pB*16 + f]); \
      } }
    PAIR2(P2)
#undef P2
  }

  // stage f32 output tile in LDS, then coalesced store
#pragma unroll
  for (int k = 0; k < 25; ++k)
    tilef[le*400 + k*16 + f] = out[k];
  __syncthreads();

  const long long base  = (long long)blockIdx.x * 6400;
  const long long total = (long long)E * 400;
  if (base + 6400 <= total){
    float* dst = outf + base;
    for (int i = threadIdx.x; i < 6400; i += 256) dst[i] = tilef[i];
  } else {
    for (int i = threadIdx.x; i < 6400 && base + i < total; i += 256) outf[base + i] = tilef[i];
  }
}

// ======================= launch =======================

extern "C" void kernel_launch(void* const* d_in, const int* in_sizes, int n_in,
                              void* d_out, int out_size, void* d_ws, size_t ws_size,
                              hipStream_t stream){
  const float* disp = (const float*)d_in[1];   // neighbour_displacements (E,3) f32
  const float* w1   = (const float*)d_in[3];   // tp_weights1 (40,16) f32
  const float* w2   = (const float*)d_in[4];   // tp_weights2 (65,16) f32
  const int E = in_sizes[1] / 3;
  const int blocks = (E + 15) / 16;
  acmd_kernel<<<blocks, 256, 0, stream>>>(disp, w1, w2, (float*)d_out, E);
}